// Round 2
// baseline (359.576 us; speedup 1.0000x reference)
//
#include <hip/hip_runtime.h>
#include <hip/hip_bf16.h>

#define BB 4
#define CC 256
#define NN 4096
#define AC2 64

typedef __attribute__((ext_vector_type(4))) float f32x4;
typedef __attribute__((ext_vector_type(8))) short bf16x8;

__device__ __forceinline__ short f2bf(float f) {
    unsigned u = __builtin_bit_cast(unsigned, f);
    u = u + 0x7FFFu + ((u >> 16) & 1u);
    return (short)(u >> 16);
}

// ---------------- Kernel 1: QKV projection ----------------
// Computes Qt[b][n][o] (o<64), Kt[b][n][o] (o<64), V[b][c][n] in bf16.
// Per block: batch b, n-tile of 64; loops c in 4 steps of 64, staging
// W[384 x 64] and X^T[64 x 64] tiles in LDS (pitch 72 to dodge conflicts).
__global__ __launch_bounds__(256) void qkv_kernel(
    const float* __restrict__ x,
    const float* __restrict__ Wq, const float* __restrict__ bq,
    const float* __restrict__ Wk, const float* __restrict__ bk,
    const float* __restrict__ Wv, const float* __restrict__ bv,
    short* __restrict__ Qt, short* __restrict__ Kt, short* __restrict__ V)
{
    __shared__ __align__(16) short Wl[384 * 72];
    __shared__ __align__(16) short Xl[64 * 72];
    const int bid = blockIdx.x;
    const int b = bid >> 6;
    const int n0 = (bid & 63) << 6;
    const int tid = threadIdx.x;
    const int lane = tid & 63, w = tid >> 6;

    f32x4 acc[6][4];
#pragma unroll
    for (int i = 0; i < 6; ++i)
#pragma unroll
        for (int j = 0; j < 4; ++j) acc[i][j] = (f32x4){0.f, 0.f, 0.f, 0.f};

    for (int ck = 0; ck < 4; ++ck) {
        const int c0 = ck * 64;
        // stage X tile transposed (read coalesced along n, write [n][c])
#pragma unroll 4
        for (int t = 0; t < 16; ++t) {
            int idx = tid + t * 256;
            int cr = idx >> 6, nc = idx & 63;
            float v = x[(((size_t)b * CC + c0 + cr) * NN) + n0 + nc];
            Xl[nc * 72 + cr] = f2bf(v);
        }
        // stage W tile [384][64]
#pragma unroll 8
        for (int t = 0; t < 96; ++t) {
            int idx = tid + t * 256;
            int o = idx >> 6, cc2 = idx & 63;
            const float* row = (o < 64) ? (Wq + o * CC)
                             : (o < 128) ? (Wk + (o - 64) * CC)
                                         : (Wv + (o - 128) * CC);
            Wl[o * 72 + cc2] = f2bf(row[c0 + cc2]);
        }
        __syncthreads();
#pragma unroll
        for (int ks = 0; ks < 2; ++ks) {
            const int co = ks * 32 + ((lane >> 4) << 3);
            bf16x8 Bf[4];
#pragma unroll
            for (int nf = 0; nf < 4; ++nf)
                Bf[nf] = *(const bf16x8*)&Xl[(nf * 16 + (lane & 15)) * 72 + co];
#pragma unroll
            for (int of = 0; of < 6; ++of) {
                bf16x8 Af = *(const bf16x8*)&Wl[((w * 6 + of) * 16 + (lane & 15)) * 72 + co];
#pragma unroll
                for (int nf = 0; nf < 4; ++nf)
                    acc[of][nf] = __builtin_amdgcn_mfma_f32_16x16x32_bf16(
                        Af, Bf[nf], acc[of][nf], 0, 0, 0);
            }
        }
        __syncthreads();
    }
    // epilogue: bias + convert + scatter to Qt / Kt / V
#pragma unroll
    for (int of = 0; of < 6; ++of) {
        const int obase = (w * 6 + of) * 16 + ((lane >> 4) << 2);
        float bias[4];
#pragma unroll
        for (int r = 0; r < 4; ++r) {
            int o = obase + r;
            bias[r] = (o < 64) ? bq[o] : (o < 128) ? bk[o - 64] : bv[o - 128];
        }
#pragma unroll
        for (int nf = 0; nf < 4; ++nf) {
            const int n = n0 + nf * 16 + (lane & 15);
            if (obase < 128) {
                short4 pk;
                pk.x = f2bf(acc[of][nf][0] + bias[0]);
                pk.y = f2bf(acc[of][nf][1] + bias[1]);
                pk.z = f2bf(acc[of][nf][2] + bias[2]);
                pk.w = f2bf(acc[of][nf][3] + bias[3]);
                short* dst = (obase < 64)
                    ? (Qt + ((size_t)b * NN + n) * AC2 + obase)
                    : (Kt + ((size_t)b * NN + n) * AC2 + (obase - 64));
                *(short4*)dst = pk;
            } else {
#pragma unroll
                for (int r = 0; r < 4; ++r) {
                    int o = obase + r - 128;
                    V[(((size_t)b * CC + o) * NN) + n] = f2bf(acc[of][nf][r] + bias[r]);
                }
            }
        }
    }
}

// ---------------- Kernel 2: column softmax stats ----------------
// For each (b, j): m_j = max_i S[i,j], rl_j = 1/sum_i exp(S[i,j]-m_j).
// Block = (b, 16-wide j tile); wave w scans i in [w*1024, w*1024+1024).
__global__ __launch_bounds__(256) void stats_kernel(
    const short* __restrict__ Qt, const short* __restrict__ Kt,
    float* __restrict__ mArr, float* __restrict__ rlArr)
{
    const int bid = blockIdx.x;
    const int b = bid >> 8;
    const int j0 = (bid & 255) << 4;
    const int tid = threadIdx.x;
    const int lane = tid & 63, w = tid >> 6;

    bf16x8 Bf[2];
#pragma unroll
    for (int ks = 0; ks < 2; ++ks)
        Bf[ks] = *(const bf16x8*)&Kt[((size_t)b * NN + j0 + (lane & 15)) * AC2 +
                                     ks * 32 + ((lane >> 4) << 3)];

    float m_run = -INFINITY, l_run = 0.f;
    for (int ii = 0; ii < 16; ++ii) {
        const int i0 = w * 1024 + ii * 64;
        f32x4 s[4];
#pragma unroll
        for (int f = 0; f < 4; ++f) {
            const size_t rowA = (size_t)b * NN + i0 + f * 16 + (lane & 15);
            bf16x8 A0 = *(const bf16x8*)&Qt[rowA * AC2 + ((lane >> 4) << 3)];
            bf16x8 A1 = *(const bf16x8*)&Qt[rowA * AC2 + 32 + ((lane >> 4) << 3)];
            f32x4 t = (f32x4){0.f, 0.f, 0.f, 0.f};
            t = __builtin_amdgcn_mfma_f32_16x16x32_bf16(A0, Bf[0], t, 0, 0, 0);
            t = __builtin_amdgcn_mfma_f32_16x16x32_bf16(A1, Bf[1], t, 0, 0, 0);
            s[f] = t;
        }
        float mx = s[0][0];
#pragma unroll
        for (int f = 0; f < 4; ++f)
#pragma unroll
            for (int r = 0; r < 4; ++r) mx = fmaxf(mx, s[f][r]);
        const float m_new = fmaxf(m_run, mx);
        float add = 0.f;
#pragma unroll
        for (int f = 0; f < 4; ++f)
#pragma unroll
            for (int r = 0; r < 4; ++r) add += __expf(s[f][r] - m_new);
        l_run = l_run * __expf(m_run - m_new) + add;
        m_run = m_new;
    }
    // combine across the 4 row-groups of the wave (lanes xor 16, 32)
#pragma unroll
    for (int off = 16; off <= 32; off <<= 1) {
        float m2 = __shfl_xor(m_run, off);
        float l2 = __shfl_xor(l_run, off);
        float mm = fmaxf(m_run, m2);
        l_run = l_run * __expf(m_run - mm) + l2 * __expf(m2 - mm);
        m_run = mm;
    }
    __shared__ float sm[4][16];
    __shared__ float sl[4][16];
    if (lane < 16) { sm[w][lane] = m_run; sl[w][lane] = l_run; }
    __syncthreads();
    if (tid < 16) {
        float m = sm[0][tid], l = sl[0][tid];
#pragma unroll
        for (int q = 1; q < 4; ++q) {
            float m2 = sm[q][tid], l2 = sl[q][tid];
            float mm = fmaxf(m, m2);
            l = l * __expf(m - mm) + l2 * __expf(m2 - mm);
            m = mm;
        }
        mArr[(size_t)b * NN + j0 + tid] = m;
        rlArr[(size_t)b * NN + j0 + tid] = 1.f / l;
    }
}

// ---------------- Kernel 3: P = exp(S-m)*rl, O = P @ V^T, residual ----------------
// Block = (b, 64-row i tile). Wave w computes S rows [16w,16w+16) and owns
// output c-strip [64w, 64w+64). P routed through padded LDS tile (C-layout ->
// A-layout conversion).
__global__ __launch_bounds__(256) void out_kernel(
    const short* __restrict__ Qt, const short* __restrict__ Kt,
    const short* __restrict__ V,
    const float* __restrict__ mArr, const float* __restrict__ rlArr,
    const float* __restrict__ x, const float* __restrict__ gamma,
    float* __restrict__ out)
{
    __shared__ __align__(16) short Pl[64 * 72];
    const int bid = blockIdx.x;
    const int b = bid >> 6;
    const int i0 = (bid & 63) << 6;
    const int tid = threadIdx.x;
    const int lane = tid & 63, w = tid >> 6;

    // Q fragments for this wave's i-strip: invariant over the j loop
    bf16x8 Aq[2];
#pragma unroll
    for (int ks = 0; ks < 2; ++ks)
        Aq[ks] = *(const bf16x8*)&Qt[((size_t)b * NN + i0 + w * 16 + (lane & 15)) * AC2 +
                                     ks * 32 + ((lane >> 4) << 3)];

    f32x4 acc[4][4];
#pragma unroll
    for (int i = 0; i < 4; ++i)
#pragma unroll
        for (int j = 0; j < 4; ++j) acc[i][j] = (f32x4){0.f, 0.f, 0.f, 0.f};

    for (int jt = 0; jt < 64; ++jt) {
        const int j0 = jt * 64;
        // S fragments (rows 16w..16w+16, cols j0..j0+64), exp, store P to LDS
#pragma unroll
        for (int jf = 0; jf < 4; ++jf) {
            const int j = j0 + jf * 16 + (lane & 15);
            f32x4 s = (f32x4){0.f, 0.f, 0.f, 0.f};
#pragma unroll
            for (int ks = 0; ks < 2; ++ks) {
                bf16x8 Bf = *(const bf16x8*)&Kt[((size_t)b * NN + j) * AC2 +
                                                ks * 32 + ((lane >> 4) << 3)];
                s = __builtin_amdgcn_mfma_f32_16x16x32_bf16(Aq[ks], Bf, s, 0, 0, 0);
            }
            const float mj = mArr[(size_t)b * NN + j];
            const float rj = rlArr[(size_t)b * NN + j];
#pragma unroll
            for (int r = 0; r < 4; ++r) {
                float p = __expf(s[r] - mj) * rj;
                Pl[(w * 16 + ((lane >> 4) << 2) + r) * 72 + jf * 16 + (lane & 15)] = f2bf(p);
            }
        }
        __syncthreads();
        // O += P @ V^T over this j tile
#pragma unroll
        for (int ks = 0; ks < 2; ++ks) {
            const int jj = j0 + ks * 32 + ((lane >> 4) << 3);
            bf16x8 Bv[4];
#pragma unroll
            for (int cf = 0; cf < 4; ++cf) {
                const int c = w * 64 + cf * 16 + (lane & 15);
                Bv[cf] = *(const bf16x8*)&V[(((size_t)b * CC + c) * NN) + jj];
            }
#pragma unroll
            for (int f = 0; f < 4; ++f) {
                bf16x8 Ap = *(const bf16x8*)&Pl[(f * 16 + (lane & 15)) * 72 +
                                                ks * 32 + ((lane >> 4) << 3)];
#pragma unroll
                for (int cf = 0; cf < 4; ++cf)
                    acc[f][cf] = __builtin_amdgcn_mfma_f32_16x16x32_bf16(
                        Ap, Bv[cf], acc[f][cf], 0, 0, 0);
            }
        }
        __syncthreads();
    }
    // epilogue: out[b][c][i] = gamma * O[i][c] + x[b][c][i]
    const float g = gamma[0];
#pragma unroll
    for (int f = 0; f < 4; ++f) {
#pragma unroll
        for (int cf = 0; cf < 4; ++cf) {
            const int c = w * 64 + cf * 16 + (lane & 15);
#pragma unroll
            for (int r = 0; r < 4; ++r) {
                const int i = i0 + f * 16 + ((lane >> 4) << 2) + r;
                const size_t idx = ((size_t)b * CC + c) * NN + i;
                out[idx] = g * acc[f][cf][r] + x[idx];
            }
        }
    }
}

extern "C" void kernel_launch(void* const* d_in, const int* in_sizes, int n_in,
                              void* d_out, int out_size, void* d_ws, size_t ws_size,
                              hipStream_t stream) {
    const float* x     = (const float*)d_in[0];
    const float* Wq    = (const float*)d_in[1];
    const float* bq    = (const float*)d_in[2];
    const float* Wk    = (const float*)d_in[3];
    const float* bk    = (const float*)d_in[4];
    const float* Wv    = (const float*)d_in[5];
    const float* bv    = (const float*)d_in[6];
    const float* gamma = (const float*)d_in[7];
    float* out = (float*)d_out;

    short* Qt = (short*)d_ws;                       // [B][N][64] bf16  (2 MB)
    short* Kt = Qt + (size_t)BB * NN * AC2;         // [B][N][64] bf16  (2 MB)
    short* V  = Kt + (size_t)BB * NN * AC2;         // [B][C][N]  bf16  (8 MB)
    float* mArr  = (float*)(V + (size_t)BB * CC * NN);  // [B][N]
    float* rlArr = mArr + (size_t)BB * NN;              // [B][N]

    qkv_kernel<<<BB * 64, 256, 0, stream>>>(x, Wq, bq, Wk, bk, Wv, bv, Qt, Kt, V);
    stats_kernel<<<BB * 256, 256, 0, stream>>>(Qt, Kt, mArr, rlArr);
    out_kernel<<<BB * 64, 256, 0, stream>>>(Qt, Kt, V, mArr, rlArr, x, gamma, out);
}